// Round 7
// baseline (96.144 us; speedup 1.0000x reference)
//
#include <hip/hip_runtime.h>
#include <hip/hip_bf16.h>
#include <math.h>

#define Bb 512
#define Tt 256
#define Cc 384
#define Hh 64

#define WPAD 72    // w_lds stride (shorts)
#define KP   72    // k_lds stride (shorts)
#define VTP  264   // vt_lds stride (shorts)
#define QBP  68    // Q bounce stride (shorts)
#define PST  40    // P tile stride (shorts)
#define WCH  12288 // chunk-major W: 192*64 shorts per k-chunk

typedef __attribute__((ext_vector_type(8))) short short8;
typedef __attribute__((ext_vector_type(4))) short short4_;
typedef __attribute__((ext_vector_type(4))) float float4_;

static __device__ __forceinline__ unsigned short f2bf(float f) {
  __hip_bfloat16 h = __float2bfloat16(f);
  return *reinterpret_cast<unsigned short*>(&h);
}

// ---------------- kernel 0: pack W chunk-major bf16: wt[ks][192][64] ----------------
// Coalesced LDS transpose; chunk-major output makes fused W loads contiguous.
__global__ __launch_bounds__(256) void wtrans_kernel(
    const float* __restrict__ wq, const float* __restrict__ wk,
    const float* __restrict__ wv, unsigned short* __restrict__ wt) {
  __shared__ float tl[384 * 8];
  const int blk = blockIdx.x;
  const int wsel = blk >> 3, n0 = (blk & 7) * 8;
  const float* w = (wsel == 0) ? wq : (wsel == 1) ? wk : wv;
  const int t = threadIdx.x;
#pragma unroll
  for (int i = 0; i < 3; i++) {          // 384 rows x 2 float4
    int id = i * 256 + t;
    int row = id >> 1, sg = id & 1;
    float4_ v = *(const float4_*)(w + row * Hh + n0 + sg * 4);
    *(float4_*)(&tl[row * 8 + sg * 4]) = v;
  }
  __syncthreads();
#pragma unroll
  for (int i = 0; i < 12; i++) {         // 8 rows x 384 cols out
    int id = i * 256 + t;
    int n = id / 384, k = id % 384;
    int row = wsel * 64 + n0 + n;
    wt[(size_t)(k >> 6) * WCH + row * 64 + (k & 63)] = f2bf(tl[k * 8 + n]);
  }
}

// ---------------- fused kernel: per-batch QKV projection + causal flash attn ----------------
// Phase A: A-operand (x) goes GLOBAL->REG directly in fragment layout (no LDS
// round-trip); only W stages through LDS, double-buffered -> 1 lgkm-only
// barrier per k-step. Phase B: scatter K/V to LDS, Q bounced to registers.
// Phase C: swapped-operand flash attn (R5/R6 verified structure).
// LDS map (shorts; 136,192 B total, 1 block/CU):
//   w0/w1  2x[192][WPAD]  W double buffer (phase A only)
//   k_lds  [256][KP]      K [seq][h]   (phase B/C)
//   vt_lds [64][VTP]      V^T [h][seq] (phase B/C)
//   r3     8*16*PST       Q bounce (B) / per-wave P tiles (C)
// launch_bounds (512,2): 256-reg budget; acc 96 + nx 64 + working ~60.
// MUST NOT cap tighter (R4: (512,4) spilled acc, 2.7x regression).
__global__ __launch_bounds__(512, 2) void fused_kernel(
    const float* __restrict__ x, const unsigned short* __restrict__ wt,
    float* __restrict__ out) {
  __shared__ unsigned short lds[2 * 192 * WPAD + 256 * KP + 64 * VTP + 8 * 16 * PST];
  unsigned short* w0     = lds;
  unsigned short* w1     = lds + 192 * WPAD;
  unsigned short* k_lds  = lds + 2 * 192 * WPAD;
  unsigned short* vt_lds = lds + 2 * 192 * WPAD + 256 * KP;
  unsigned short* r3     = lds + 2 * 192 * WPAD + 256 * KP + 64 * VTP;

  const int t = threadIdx.x;
  const int wid = t >> 6, lane = t & 63;
  const int fr = lane & 15, fg = lane >> 4;
  const int wr = wid >> 1, wc = wid & 1;   // 4x2 wave grid: 64 rows x 96 cols each
  const int b = blockIdx.x;
  const float* xb = x + (size_t)b * Tt * Cc;
  // per-lane A-row base: row = wr*64 + mi*16 + fr, cols fg*8..
  const float* xw = xb + (size_t)(wr * 64 + fr) * Cc + fg * 8;

  // ================= phase A: QKV = x[b] @ W  (M=256, N=192, K=384) =================
  float4_ acc[4][6];
#pragma unroll
  for (int i = 0; i < 4; i++)
#pragma unroll
    for (int j = 0; j < 6; j++) acc[i][j] = (float4_)0.f;

  // A fragments for chunk 0, direct to registers (16 rows x 128B per wave-inst)
  float4_ nx[4][2][2];
#pragma unroll
  for (int mi = 0; mi < 4; mi++)
#pragma unroll
    for (int kk = 0; kk < 2; kk++)
#pragma unroll
      for (int h = 0; h < 2; h++)
        nx[mi][kk][h] = *(const float4_*)(xw + mi * 16 * Cc + kk * 32 + h * 4);

  // W chunk 0 -> regs -> w0
  short8 wvv[3];
#pragma unroll
  for (int i = 0; i < 3; i++) {
    int id = t + i * 512;
    wvv[i] = *(const short8*)(wt + (id >> 3) * 64 + (id & 7) * 8);
  }
#pragma unroll
  for (int i = 0; i < 3; i++) {
    int id = t + i * 512;
    *(short8*)(&w0[(id >> 3) * WPAD + (id & 7) * 8]) = wvv[i];
  }

#pragma unroll
  for (int ks = 0; ks < 6; ks++) {
    // convert this chunk's A to bf16 fragments (vmcnt waits land here)
    short8 af[4][2];
#pragma unroll
    for (int mi = 0; mi < 4; mi++)
#pragma unroll
      for (int kk = 0; kk < 2; kk++)
#pragma unroll
        for (int h = 0; h < 2; h++)
#pragma unroll
          for (int j = 0; j < 4; j++)
            af[mi][kk][h * 4 + j] = (short)f2bf(nx[mi][kk][h][j]);
    if (ks < 5) {
      // issue next A chunk (covered by this iteration's MFMA phase)
#pragma unroll
      for (int mi = 0; mi < 4; mi++)
#pragma unroll
        for (int kk = 0; kk < 2; kk++)
#pragma unroll
          for (int h = 0; h < 2; h++)
            nx[mi][kk][h] = *(const float4_*)(xw + mi * 16 * Cc + (ks + 1) * 64 + kk * 32 + h * 4);
      // next W chunk -> regs (L2-hot, contiguous chunk-major)
#pragma unroll
      for (int i = 0; i < 3; i++) {
        int id = t + i * 512;
        wvv[i] = *(const short8*)(wt + (ks + 1) * WCH + (id >> 3) * 64 + (id & 7) * 8);
      }
    }
    // single barrier per iter: prev iter's W-buffer writes visible; vm loads in flight
    asm volatile("s_waitcnt lgkmcnt(0)" ::: "memory");
    __builtin_amdgcn_s_barrier();
    __builtin_amdgcn_sched_barrier(0);
    unsigned short* wb = (ks & 1) ? w1 : w0;
#pragma unroll
    for (int kk = 0; kk < 2; kk++) {
      short8 bfr[6];
#pragma unroll
      for (int ni = 0; ni < 6; ni++)
        bfr[ni] = *(const short8*)(&wb[(wc * 96 + ni * 16 + fr) * WPAD + kk * 32 + fg * 8]);
#pragma unroll
      for (int mi = 0; mi < 4; mi++)
#pragma unroll
        for (int ni = 0; ni < 6; ni++)
          acc[mi][ni] = __builtin_amdgcn_mfma_f32_16x16x32_bf16(af[mi][kk], bfr[ni], acc[mi][ni], 0, 0, 0);
    }
    if (ks < 5) {   // write next W chunk into the other buffer (no reader yet)
      unsigned short* wn = (ks & 1) ? w0 : w1;
#pragma unroll
      for (int i = 0; i < 3; i++) {
        int id = t + i * 512;
        *(short8*)(&wn[(id >> 3) * WPAD + (id & 7) * 8]) = wvv[i];
      }
    }
  }
  __syncthreads();   // end phase A (all vm consumed; LDS reads done)

  // ================= phase B: scatter K/V; bounce Q to registers =================
  // acc D-layout: row = wr*64 + mi*16 + fg*4 + r, col = wc*96 + ni*16 + fr
#pragma unroll
  for (int mi = 0; mi < 4; mi++) {
    int row0 = wr * 64 + mi * 16 + fg * 4;
#pragma unroll
    for (int ni = 0; ni < 6; ni++) {
      int col = wc * 96 + ni * 16 + fr;
      if (wc == 1 && ni >= 2) {          // V cols 128..191 -> V^T [h][seq]
        short4_ pk;
#pragma unroll
        for (int r = 0; r < 4; r++) pk[r] = (short)f2bf(acc[mi][ni][r]);
        *(short4_*)(&vt_lds[(col - 128) * VTP + row0]) = pk;
      } else if (!(wc == 0 && ni < 4)) { // K cols 64..127 -> [seq][h]
#pragma unroll
        for (int r = 0; r < 4; r++)
          k_lds[(row0 + r) * KP + (col - 64)] = f2bf(acc[mi][ni][r]);
      }
    }
  }

  // Q bounce: 4 rounds through r3; each wave ends with A-frag-style Q regs
  short8 aqA0 = {}, aqA1 = {}, aqB0 = {}, aqB1 = {};
  const int qtA = wid, qtB = 15 - wid;   // balanced causal split (9 kt-steps each)
  for (int rd = 0; rd < 4; rd++) {
    if (rd) __syncthreads();            // previous round's consumers done
    if (wid == 2 * rd) {                // producer wave (wc==0, wr==rd): tiles rd*4+mi
#pragma unroll
      for (int mi = 0; mi < 4; mi++)
#pragma unroll
        for (int ni = 0; ni < 4; ni++)
#pragma unroll
          for (int r = 0; r < 4; r++)
            r3[(mi * 16 + fg * 4 + r) * QBP + ni * 16 + fr] = f2bf(acc[mi][ni][r]);
    }
    __syncthreads();
    if ((qtA >> 2) == rd) {
      int tl = qtA & 3;
      aqA0 = *(const short8*)(&r3[(tl * 16 + fr) * QBP + fg * 8]);
      aqA1 = *(const short8*)(&r3[(tl * 16 + fr) * QBP + 32 + fg * 8]);
    }
    if ((qtB >> 2) == rd) {
      int tl = qtB & 3;
      aqB0 = *(const short8*)(&r3[(tl * 16 + fr) * QBP + fg * 8]);
      aqB1 = *(const short8*)(&r3[(tl * 16 + fr) * QBP + 32 + fg * 8]);
    }
  }
  __syncthreads();   // bounce done before r3 becomes P tiles

  // ================= phase C: causal flash attn, swapped-operand layout =================
  unsigned short* pw = r3 + wid * 16 * PST;   // wave-private P tile [16 q][32 k]
  const float SC  = 0.05103103630798288f;     // 384^-0.5
  const float L2E = 1.4426950408889634f;

  auto run_tile = [&](int qt, short8 aq0, short8 aq1) {
    float4_ o[4] = {(float4_)0.f, (float4_)0.f, (float4_)0.f, (float4_)0.f};
    float m = -3.0e38f, l = 0.f;
    const int qg = qt * 16 + fr;   // this lane's q row
    const int ktmax = qt >> 1;
    // preload kt=0 fragments (K and V^T)
    short8 kf0 = *(const short8*)(&k_lds[fr * KP + fg * 8]);
    short8 kf1 = *(const short8*)(&k_lds[(16 + fr) * KP + fg * 8]);
    short8 kf2 = *(const short8*)(&k_lds[fr * KP + 32 + fg * 8]);
    short8 kf3 = *(const short8*)(&k_lds[(16 + fr) * KP + 32 + fg * 8]);
    short8 bv0 = *(const short8*)(&vt_lds[fr * VTP + fg * 8]);
    short8 bv1 = *(const short8*)(&vt_lds[(16 + fr) * VTP + fg * 8]);
    short8 bv2 = *(const short8*)(&vt_lds[(32 + fr) * VTP + fg * 8]);
    short8 bv3 = *(const short8*)(&vt_lds[(48 + fr) * VTP + fg * 8]);
    for (int kt = 0; kt <= ktmax; kt++) {
      // S^T = K . Q^T : lane holds q=fr, k = half*16 + fg*4 + r
      float4_ s0 = (float4_)0.f, s1 = (float4_)0.f;
      s0 = __builtin_amdgcn_mfma_f32_16x16x32_bf16(kf0, aq0, s0, 0, 0, 0);
      s1 = __builtin_amdgcn_mfma_f32_16x16x32_bf16(kf1, aq0, s1, 0, 0, 0);
      s0 = __builtin_amdgcn_mfma_f32_16x16x32_bf16(kf2, aq1, s0, 0, 0, 0);
      s1 = __builtin_amdgcn_mfma_f32_16x16x32_bf16(kf3, aq1, s1, 0, 0, 0);
      // reload K frags for kt+1 (kf consumed); latency hides under softmax
      if (kt < ktmax) {
        int kb = (kt + 1) * 32;
        kf0 = *(const short8*)(&k_lds[(kb + fr) * KP + fg * 8]);
        kf1 = *(const short8*)(&k_lds[(kb + 16 + fr) * KP + fg * 8]);
        kf2 = *(const short8*)(&k_lds[(kb + fr) * KP + 32 + fg * 8]);
        kf3 = *(const short8*)(&k_lds[(kb + 16 + fr) * KP + 32 + fg * 8]);
      }
      bool edge = (kt == ktmax);
      float vs[8];
#pragma unroll
      for (int r = 0; r < 4; r++) {
        int kg0 = kt * 32 + fg * 4 + r;
        float a0 = s0[r] * SC, a1 = s1[r] * SC;
        if (edge && kg0 > qg)      a0 = -3.0e38f;
        if (edge && kg0 + 16 > qg) a1 = -3.0e38f;
        vs[r] = a0; vs[4 + r] = a1;
      }
      // lane-local 8-way max + 2-level butterfly (fg groups share q=fr)
      float mx = fmaxf(fmaxf(fmaxf(vs[0], vs[1]), fmaxf(vs[2], vs[3])),
                       fmaxf(fmaxf(vs[4], vs[5]), fmaxf(vs[6], vs[7])));
      mx = fmaxf(mx, __shfl_xor(mx, 16));
      mx = fmaxf(mx, __shfl_xor(mx, 32));
      // defer-rescale (T13, THR=8): skip O/l rescale when max growth is small
      if (!__all(mx - m <= 8.0f)) {
        float mn = fmaxf(m, mx);
        float scal = exp2f((m - mn) * L2E);
        l *= scal;
#pragma unroll
        for (int nt = 0; nt < 4; nt++) o[nt] *= scal;
        m = mn;
      }
      float p[8]; float ps = 0.f;
#pragma unroll
      for (int j = 0; j < 8; j++) { p[j] = exp2f((vs[j] - m) * L2E); ps += p[j]; }
      ps += __shfl_xor(ps, 16);
      ps += __shfl_xor(ps, 32);
      l += ps;

      // P -> p_lds [q=fr][k]: two b64 writes, one b128 read as B-frag
      short4_ pk0, pk1;
#pragma unroll
      for (int r = 0; r < 4; r++) { pk0[r] = (short)f2bf(p[r]); pk1[r] = (short)f2bf(p[4 + r]); }
      *(short4_*)(&pw[fr * PST + fg * 4]) = pk0;
      *(short4_*)(&pw[fr * PST + 16 + fg * 4]) = pk1;
      asm volatile("s_waitcnt lgkmcnt(0)" ::: "memory");
      __builtin_amdgcn_sched_barrier(0);
      short8 pb = *(const short8*)(&pw[fr * PST + fg * 8]);
      // O^T += V^T . P : A-frag = V^T rows (h=nt*16+fr), B-frag = P
      o[0] = __builtin_amdgcn_mfma_f32_16x16x32_bf16(bv0, pb, o[0], 0, 0, 0);
      o[1] = __builtin_amdgcn_mfma_f32_16x16x32_bf16(bv1, pb, o[1], 0, 0, 0);
      o[2] = __builtin_amdgcn_mfma_f32_16x16x32_bf16(bv2, pb, o[2], 0, 0, 0);
      o[3] = __builtin_amdgcn_mfma_f32_16x16x32_bf16(bv3, pb, o[3], 0, 0, 0);
      // reload V^T frags for kt+1 (bv consumed); latency hides under next QK+softmax
      if (kt < ktmax) {
        int kb = (kt + 1) * 32;
        bv0 = *(const short8*)(&vt_lds[fr * VTP + kb + fg * 8]);
        bv1 = *(const short8*)(&vt_lds[(16 + fr) * VTP + kb + fg * 8]);
        bv2 = *(const short8*)(&vt_lds[(32 + fr) * VTP + kb + fg * 8]);
        bv3 = *(const short8*)(&vt_lds[(48 + fr) * VTP + kb + fg * 8]);
      }
    }
    // epilogue: O^T[h=nt*16+fg*4+r][q=fr] / l  -> coalesced float4 stores
    float inv = 1.f / l;
#pragma unroll
    for (int nt = 0; nt < 4; nt++) {
      float4_ ov = o[nt] * inv;
      *(float4_*)(&out[((size_t)b * Tt + qt * 16 + fr) * Hh + nt * 16 + fg * 4]) = ov;
    }
  };
  run_tile(qtA, aqA0, aqA1);
  run_tile(qtB, aqB0, aqB1);
}

extern "C" void kernel_launch(void* const* d_in, const int* in_sizes, int n_in,
                              void* d_out, int out_size, void* d_ws, size_t ws_size,
                              hipStream_t stream) {
  const float* x  = (const float*)d_in[0];
  const float* wq = (const float*)d_in[1];
  const float* wk = (const float*)d_in[2];
  const float* wv = (const float*)d_in[3];
  unsigned short* wt = (unsigned short*)d_ws;   // 6 chunks x 192*64 bf16
  float* out = (float*)d_out;

  hipLaunchKernelGGL(wtrans_kernel, dim3(24), dim3(256), 0, stream, wq, wk, wv, wt);
  hipLaunchKernelGGL(fused_kernel,  dim3(Bb), dim3(512), 0, stream, x, wt, out);
}

// Round 8
// 69.319 us; speedup vs baseline: 1.3870x; 1.3870x over previous
//
#include <hip/hip_runtime.h>
#include <hip/hip_bf16.h>
#include <math.h>

#define Bb 512
#define Tt 256
#define Cc 384
#define Hh 64

#define APAD 72    // a_lds / k_lds stride (shorts)
#define WPAD 72    // w_lds stride (shorts)
#define VTP  264   // vt_lds stride (shorts)
#define QBP  72    // q_lds stride (shorts)
#define PST  40    // P tile stride (shorts)

typedef __attribute__((ext_vector_type(8))) short short8;
typedef __attribute__((ext_vector_type(4))) short short4_;
typedef __attribute__((ext_vector_type(4))) float float4_;

static __device__ __forceinline__ unsigned short f2bf(float f) {
  __hip_bfloat16 h = __float2bfloat16(f);
  return *reinterpret_cast<unsigned short*>(&h);
}

// ---------------- kernel 0: pack W into transposed bf16 wt[192][384] ----------------
__global__ __launch_bounds__(256) void wtrans_kernel(
    const float* __restrict__ wq, const float* __restrict__ wk,
    const float* __restrict__ wv, unsigned short* __restrict__ wt) {
  __shared__ float tl[384 * 8];
  const int blk = blockIdx.x;
  const int wsel = blk >> 3, n0 = (blk & 7) * 8;
  const float* w = (wsel == 0) ? wq : (wsel == 1) ? wk : wv;
  const int t = threadIdx.x;
#pragma unroll
  for (int i = 0; i < 3; i++) {          // 384 rows x 2 float4
    int id = i * 256 + t;
    int row = id >> 1, sg = id & 1;
    float4_ v = *(const float4_*)(w + row * Hh + n0 + sg * 4);
    *(float4_*)(&tl[row * 8 + sg * 4]) = v;
  }
  __syncthreads();
#pragma unroll
  for (int i = 0; i < 12; i++) {         // 8 rows x 384 cols out
    int id = i * 256 + t;
    int n = id / 384, k = id % 384;
    wt[(size_t)(wsel * 64 + n0 + n) * Cc + k] = f2bf(tl[k * 8 + n]);
  }
}

// ---------------- fused kernel: per-batch QKV projection + causal flash attn ----------------
// LDS map (117,760 B; 1 block/CU):
//   region1 [256][APAD] : phase A = x-chunk bf16 staging; phase B/C = K
//   region2 [64][VTP]   : phase A = W staging (192*WPAD fits); phase B/C = V^T
//   region3 [256][QBP]  : phase B/C = Q
//   region4 8*16*PST    : phase C = per-wave P tiles
// __launch_bounds__ 2nd arg is CUDA-semantics BLOCKS/CU (verified: R4 (512,4)
// -> 64 VGPR; R3/R7 (512,2) -> 120/128 VGPR). (512,1) = 256-VGPR budget; LDS
// already limits to 1 block/CU, so this costs no occupancy.
__global__ __launch_bounds__(512, 1) void fused_kernel(
    const float* __restrict__ x, const unsigned short* __restrict__ wt,
    float* __restrict__ out) {
  __shared__ unsigned short lds[256 * APAD + 64 * VTP + 256 * QBP + 8 * 16 * PST];
  unsigned short* a_lds  = lds;
  unsigned short* k_lds  = lds;                        // alias (phase-disjoint)
  unsigned short* w_lds  = lds + 256 * APAD;
  unsigned short* vt_lds = lds + 256 * APAD;           // alias (phase-disjoint)
  unsigned short* q_lds  = lds + 256 * APAD + 64 * VTP;
  unsigned short* r3     = lds + 256 * APAD + 64 * VTP + 256 * QBP;

  const int t = threadIdx.x;
  const int wid = t >> 6, lane = t & 63;
  const int fr = lane & 15, fg = lane >> 4;
  const int wr = wid >> 1, wc = wid & 1;   // 4x2 wave grid: 64 rows x 96 cols each
  const int b = blockIdx.x;
  const float* xb = x + (size_t)b * Tt * Cc;

  // ================= phase A: QKV = x[b] @ W  (M=256, N=192, K=384) =================
  float4_ acc[4][6];
#pragma unroll
  for (int i = 0; i < 4; i++)
#pragma unroll
    for (int j = 0; j < 6; j++) acc[i][j] = (float4_)0.f;

  // 2-deep register prefetch: chunk k's loads get a full iteration in flight
  float4_ av[2][8];
#pragma unroll
  for (int buf = 0; buf < 2; buf++)
#pragma unroll
    for (int i = 0; i < 8; i++) {
      int f = i * 512 + t;
      av[buf][i] = *(const float4_*)(xb + (f >> 4) * Cc + buf * 64 + (f & 15) * 4);
    }

#pragma unroll
  for (int ks = 0; ks < 6; ks++) {
    const int cur = ks & 1;
    if (ks) {   // barrier A: prev MFMA LDS reads done; vm loads stay in flight
      asm volatile("s_waitcnt lgkmcnt(0)" ::: "memory");
      __builtin_amdgcn_s_barrier();
      __builtin_amdgcn_sched_barrier(0);
    }
    // W chunk loads first (L2-hot): latency hides under the av vmcnt wait below
    short8 wv[3];
#pragma unroll
    for (int i = 0; i < 3; i++) {
      int id = t + i * 512;
      wv[i] = *(const short8*)(wt + (id >> 3) * Cc + ks * 64 + (id & 7) * 8);
    }
    // stage A: prefetched f32 -> bf16 LDS (compiler emits vmcnt wait here)
#pragma unroll
    for (int i = 0; i < 8; i++) {
      int f = i * 512 + t;
      short4_ pk;
#pragma unroll
      for (int j = 0; j < 4; j++) pk[j] = (short)f2bf(av[cur][i][j]);
      *(short4_*)(&a_lds[(f >> 4) * APAD + (f & 15) * 4]) = pk;
    }
    // issue chunk ks+2 into the buffer just consumed
    if (ks < 4) {
#pragma unroll
      for (int i = 0; i < 8; i++) {
        int f = i * 512 + t;
        av[cur][i] = *(const float4_*)(xb + (f >> 4) * Cc + (ks + 2) * 64 + (f & 15) * 4);
      }
    }
    // W store
#pragma unroll
    for (int i = 0; i < 3; i++) {
      int id = t + i * 512;
      *(short8*)(&w_lds[(id >> 3) * WPAD + (id & 7) * 8]) = wv[i];
    }
    // barrier B: staging visible; only lgkm drained (av loads NOT drained)
    asm volatile("s_waitcnt lgkmcnt(0)" ::: "memory");
    __builtin_amdgcn_s_barrier();
    __builtin_amdgcn_sched_barrier(0);
#pragma unroll
    for (int kk = 0; kk < 2; kk++) {
      short8 af[4], bf[6];
#pragma unroll
      for (int mi = 0; mi < 4; mi++)
        af[mi] = *(const short8*)(&a_lds[(wr * 64 + mi * 16 + fr) * APAD + kk * 32 + fg * 8]);
#pragma unroll
      for (int ni = 0; ni < 6; ni++)
        bf[ni] = *(const short8*)(&w_lds[(wc * 96 + ni * 16 + fr) * WPAD + kk * 32 + fg * 8]);
#pragma unroll
      for (int mi = 0; mi < 4; mi++)
#pragma unroll
        for (int ni = 0; ni < 6; ni++)
          acc[mi][ni] = __builtin_amdgcn_mfma_f32_16x16x32_bf16(af[mi], bf[ni], acc[mi][ni], 0, 0, 0);
    }
  }

  __syncthreads();   // end phase A: all LDS reads done before aliased overwrite

  // ================= phase B: scatter Q/K/V into attention layouts =================
  // acc D-layout: row = wr*64 + mi*16 + fg*4 + r, col = wc*96 + ni*16 + fr
#pragma unroll
  for (int mi = 0; mi < 4; mi++) {
    int row0 = wr * 64 + mi * 16 + fg * 4;
#pragma unroll
    for (int ni = 0; ni < 6; ni++) {
      int col = wc * 96 + ni * 16 + fr;
      if (wc == 1 && ni >= 2) {          // V cols 128..191 -> V^T [h][seq]
        short4_ pk;
#pragma unroll
        for (int r = 0; r < 4; r++) pk[r] = (short)f2bf(acc[mi][ni][r]);
        *(short4_*)(&vt_lds[(col - 128) * VTP + row0]) = pk;
      } else if (wc == 0 && ni < 4) {    // Q cols 0..63 -> [seq][h]
#pragma unroll
        for (int r = 0; r < 4; r++)
          q_lds[(row0 + r) * QBP + col] = f2bf(acc[mi][ni][r]);
      } else {                           // K cols 64..127 -> [seq][h]
#pragma unroll
        for (int r = 0; r < 4; r++)
          k_lds[(row0 + r) * APAD + (col - 64)] = f2bf(acc[mi][ni][r]);
      }
    }
  }
  __syncthreads();

  // ================= phase C: causal flash attn, swapped-operand layout =================
  unsigned short* pw = r3 + wid * 16 * PST;   // wave-private P tile [16 q][32 k]
  const float SC  = 0.05103103630798288f;     // 384^-0.5
  const float L2E = 1.4426950408889634f;

  auto run_tile = [&](int qt) {
    short8 aq0 = *(const short8*)(&q_lds[(qt * 16 + fr) * QBP + fg * 8]);
    short8 aq1 = *(const short8*)(&q_lds[(qt * 16 + fr) * QBP + 32 + fg * 8]);
    float4_ o[4] = {(float4_)0.f, (float4_)0.f, (float4_)0.f, (float4_)0.f};
    float m = -3.0e38f, l = 0.f;
    const int qg = qt * 16 + fr;   // this lane's q row
    const int ktmax = qt >> 1;
    // preload kt=0 fragments (K and V^T)
    short8 kf0 = *(const short8*)(&k_lds[fr * APAD + fg * 8]);
    short8 kf1 = *(const short8*)(&k_lds[(16 + fr) * APAD + fg * 8]);
    short8 kf2 = *(const short8*)(&k_lds[fr * APAD + 32 + fg * 8]);
    short8 kf3 = *(const short8*)(&k_lds[(16 + fr) * APAD + 32 + fg * 8]);
    short8 bv0 = *(const short8*)(&vt_lds[fr * VTP + fg * 8]);
    short8 bv1 = *(const short8*)(&vt_lds[(16 + fr) * VTP + fg * 8]);
    short8 bv2 = *(const short8*)(&vt_lds[(32 + fr) * VTP + fg * 8]);
    short8 bv3 = *(const short8*)(&vt_lds[(48 + fr) * VTP + fg * 8]);
    for (int kt = 0; kt <= ktmax; kt++) {
      // S^T = K . Q^T : lane holds q=fr, k = half*16 + fg*4 + r
      float4_ s0 = (float4_)0.f, s1 = (float4_)0.f;
      s0 = __builtin_amdgcn_mfma_f32_16x16x32_bf16(kf0, aq0, s0, 0, 0, 0);
      s1 = __builtin_amdgcn_mfma_f32_16x16x32_bf16(kf1, aq0, s1, 0, 0, 0);
      s0 = __builtin_amdgcn_mfma_f32_16x16x32_bf16(kf2, aq1, s0, 0, 0, 0);
      s1 = __builtin_amdgcn_mfma_f32_16x16x32_bf16(kf3, aq1, s1, 0, 0, 0);
      // reload K frags for kt+1 (kf consumed); latency hides under softmax
      if (kt < ktmax) {
        int kb = (kt + 1) * 32;
        kf0 = *(const short8*)(&k_lds[(kb + fr) * APAD + fg * 8]);
        kf1 = *(const short8*)(&k_lds[(kb + 16 + fr) * APAD + fg * 8]);
        kf2 = *(const short8*)(&k_lds[(kb + fr) * APAD + 32 + fg * 8]);
        kf3 = *(const short8*)(&k_lds[(kb + 16 + fr) * APAD + 32 + fg * 8]);
      }
      bool edge = (kt == ktmax);
      float vs[8];
#pragma unroll
      for (int r = 0; r < 4; r++) {
        int kg0 = kt * 32 + fg * 4 + r;
        float a0 = s0[r] * SC, a1 = s1[r] * SC;
        if (edge && kg0 > qg)      a0 = -3.0e38f;
        if (edge && kg0 + 16 > qg) a1 = -3.0e38f;
        vs[r] = a0; vs[4 + r] = a1;
      }
      // lane-local 8-way max + 2-level butterfly (fg groups share q=fr)
      float mx = fmaxf(fmaxf(fmaxf(vs[0], vs[1]), fmaxf(vs[2], vs[3])),
                       fmaxf(fmaxf(vs[4], vs[5]), fmaxf(vs[6], vs[7])));
      mx = fmaxf(mx, __shfl_xor(mx, 16));
      mx = fmaxf(mx, __shfl_xor(mx, 32));
      // defer-rescale (T13, THR=8): skip O/l rescale when max growth is small
      if (!__all(mx - m <= 8.0f)) {
        float mn = fmaxf(m, mx);
        float scal = exp2f((m - mn) * L2E);
        l *= scal;
#pragma unroll
        for (int nt = 0; nt < 4; nt++) o[nt] *= scal;
        m = mn;
      }
      float p[8]; float ps = 0.f;
#pragma unroll
      for (int j = 0; j < 8; j++) { p[j] = exp2f((vs[j] - m) * L2E); ps += p[j]; }
      ps += __shfl_xor(ps, 16);
      ps += __shfl_xor(ps, 32);
      l += ps;

      // P -> p_lds [q=fr][k]: two b64 writes, one b128 read as B-frag
      short4_ pk0, pk1;
#pragma unroll
      for (int r = 0; r < 4; r++) { pk0[r] = (short)f2bf(p[r]); pk1[r] = (short)f2bf(p[4 + r]); }
      *(short4_*)(&pw[fr * PST + fg * 4]) = pk0;
      *(short4_*)(&pw[fr * PST + 16 + fg * 4]) = pk1;
      asm volatile("s_waitcnt lgkmcnt(0)" ::: "memory");
      __builtin_amdgcn_sched_barrier(0);
      short8 pb = *(const short8*)(&pw[fr * PST + fg * 8]);
      // O^T += V^T . P : A-frag = V^T rows (h=nt*16+fr), B-frag = P
      o[0] = __builtin_amdgcn_mfma_f32_16x16x32_bf16(bv0, pb, o[0], 0, 0, 0);
      o[1] = __builtin_amdgcn_mfma_f32_16x16x32_bf16(bv1, pb, o[1], 0, 0, 0);
      o[2] = __builtin_amdgcn_mfma_f32_16x16x32_bf16(bv2, pb, o[2], 0, 0, 0);
      o[3] = __builtin_amdgcn_mfma_f32_16x16x32_bf16(bv3, pb, o[3], 0, 0, 0);
      // reload V^T frags for kt+1 (bv consumed); latency hides under next QK+softmax
      if (kt < ktmax) {
        int kb = (kt + 1) * 32;
        bv0 = *(const short8*)(&vt_lds[fr * VTP + kb + fg * 8]);
        bv1 = *(const short8*)(&vt_lds[(16 + fr) * VTP + kb + fg * 8]);
        bv2 = *(const short8*)(&vt_lds[(32 + fr) * VTP + kb + fg * 8]);
        bv3 = *(const short8*)(&vt_lds[(48 + fr) * VTP + kb + fg * 8]);
      }
    }
    // epilogue: O^T[h=nt*16+fg*4+r][q=fr] / l  -> coalesced float4 stores
    float inv = 1.f / l;
#pragma unroll
    for (int nt = 0; nt < 4; nt++) {
      float4_ ov = o[nt] * inv;
      *(float4_*)(&out[((size_t)b * Tt + qt * 16 + fr) * Hh + nt * 16 + fg * 4]) = ov;
    }
  };
  run_tile(wid);        // balanced causal split: 9 kt-steps per wave total
  run_tile(15 - wid);
}

extern "C" void kernel_launch(void* const* d_in, const int* in_sizes, int n_in,
                              void* d_out, int out_size, void* d_ws, size_t ws_size,
                              hipStream_t stream) {
  const float* x  = (const float*)d_in[0];
  const float* wq = (const float*)d_in[1];
  const float* wk = (const float*)d_in[2];
  const float* wv = (const float*)d_in[3];
  unsigned short* wt = (unsigned short*)d_ws;   // 192*384 bf16
  float* out = (float*)d_out;

  hipLaunchKernelGGL(wtrans_kernel, dim3(24), dim3(256), 0, stream, wq, wk, wv, wt);
  hipLaunchKernelGGL(fused_kernel,  dim3(Bb), dim3(512), 0, stream, x, wt, out);
}